// Round 8
// baseline (177.556 us; speedup 1.0000x reference)
//
#include <hip/hip_runtime.h>

#define BB 64
#define LL 512
#define SS 512
#define HH 768
#define CC 9
#define WPB 32                          // words per block
#define NBLK (BB * SS / WPB)            // 1024 blocks, 16 per batch
#define MAXROWS (WPB * 3)               // 96 subword rows max per block
#define WTPAD 772                       // 768+4 floats, rows 16B aligned
#define RLST 12                         // row-logit LDS stride (floats)

// DPP full-wave (64-lane) sum; total lands in lane 63. Pure VALU, no LDS.
template <int CTRL>
__device__ __forceinline__ float dpp_add(float x) {
    int y = __builtin_amdgcn_update_dpp(0, __float_as_int(x), CTRL, 0xf, 0xf, true);
    return x + __int_as_float(y);
}
__device__ __forceinline__ float rsum64(float x) {
    x = dpp_add<0x111>(x);  // row_shr:1
    x = dpp_add<0x112>(x);  // row_shr:2
    x = dpp_add<0x114>(x);  // row_shr:4
    x = dpp_add<0x118>(x);  // row_shr:8
    x = dpp_add<0x142>(x);  // row_bcast:15
    x = dpp_add<0x143>(x);  // row_bcast:31 -> lane 63 = full sum
    return x;
}

// Fused: per-block word-range scan + streaming row-logit GEMM + pool + softmax.
__global__ __launch_bounds__(256) void fused_kernel(
    const float* __restrict__ bert,     // [B*L, H]
    const float* __restrict__ Wm,       // [H, C]
    const float* __restrict__ bias,     // [C]
    const int* __restrict__ ids_lens,   // [B, S]
    const int* __restrict__ label_ids,  // [B, S]
    float* __restrict__ pred_out,       // d_out + 1
    float* __restrict__ nll_part,       // [NBLK]
    float* __restrict__ cnt_part)       // [NBLK]
{
    __shared__ __align__(16) float WT[CC][WTPAD];
    __shared__ __align__(16) float RLs[MAXROWS][RLST];
    __shared__ int wlen[WPB], woff[WPB];
    __shared__ int s_meta[2];           // [start0, rows_n]
    __shared__ float red[4];

    int b = blockIdx.x >> 4;            // batch
    int q = blockIdx.x & 15;            // quarter... 16 slices per batch
    int w0 = q * WPB;                   // first word of slice
    const int* lens = ids_lens + b * SS;

    int t = threadIdx.x, lane = t & 63, wave = t >> 6;

    // Stage W transposed into LDS (coalesced), once per block
    for (int i = t; i < HH * CC; i += 256) {
        int h = i / CC;
        int c = i - h * CC;
        WT[c][h] = Wm[i];
    }
    // Stage this slice's 32 lens
    if (t < WPB) wlen[t] = lens[w0 + t];

    // Block-reduce sum of lens[0..w0) -> slice's first subword offset
    int part = 0;
    for (int i = t; i < w0; i += 256) part += lens[i];
    float pf = rsum64((float)part);     // counts < 1536, exact in fp32
    if (lane == 63) red[wave] = pf;
    __syncthreads();
    if (t == 0) {
        int start0 = (int)(red[0] + red[1] + red[2] + red[3]);
        int run = 0;
#pragma unroll
        for (int k = 0; k < WPB; k++) { woff[k] = run; run += wlen[k]; }
        s_meta[0] = start0;
        s_meta[1] = run;                // rows in this slice
    }
    __syncthreads();
    int start0 = s_meta[0];
    int rows_n = s_meta[1];

    // Lane's W slice into registers: 9 x 3 float4 = 108 VGPRs
    int hoff = lane * 4;
    float4 wreg[CC][3];
#pragma unroll
    for (int c = 0; c < CC; c++)
#pragma unroll
        for (int c3 = 0; c3 < 3; c3++)
            wreg[c][c3] = *reinterpret_cast<const float4*>(&WT[c][c3 * 256 + hoff]);

    // Phase 1: stream this slice's contiguous bert rows -> row logits in LDS
    for (int r = wave; r < rows_n; r += 4) {
        const float* p = bert + ((size_t)(b * LL + start0 + r)) * HH + hoff;
        float4 f0 = *reinterpret_cast<const float4*>(p);
        float4 f1 = *reinterpret_cast<const float4*>(p + 256);
        float4 f2 = *reinterpret_cast<const float4*>(p + 512);

        float acc[CC];
#pragma unroll
        for (int c = 0; c < CC; c++) {
            acc[c] = f0.x * wreg[c][0].x + f0.y * wreg[c][0].y
                   + f0.z * wreg[c][0].z + f0.w * wreg[c][0].w
                   + f1.x * wreg[c][1].x + f1.y * wreg[c][1].y
                   + f1.z * wreg[c][1].z + f1.w * wreg[c][1].w
                   + f2.x * wreg[c][2].x + f2.y * wreg[c][2].y
                   + f2.z * wreg[c][2].z + f2.w * wreg[c][2].w;
        }
#pragma unroll
        for (int c = 0; c < CC; c++) acc[c] = rsum64(acc[c]);

        if (lane == 63) {
            float4 s0; s0.x = acc[0]; s0.y = acc[1]; s0.z = acc[2]; s0.w = acc[3];
            float4 s1; s1.x = acc[4]; s1.y = acc[5]; s1.z = acc[6]; s1.w = acc[7];
            *reinterpret_cast<float4*>(&RLs[r][0]) = s0;
            *reinterpret_cast<float4*>(&RLs[r][4]) = s1;
            RLs[r][8] = acc[8];
        }
    }
    __syncthreads();

    // Phase 2: wave 0 pools the 32 words (lanes 32..63 ride along with len=0)
    if (t < 64) {
        int k = t;
        bool active = k < WPB;
        int len = active ? wlen[k] : 0;
        int off = active ? woff[k] : 0;

        float s[CC];
#pragma unroll
        for (int c = 0; c < CC; c++) s[c] = 0.0f;
        for (int j = 0; j < len; ++j) {
            const float* p = &RLs[off + j][0];
            float4 a = *reinterpret_cast<const float4*>(p);
            float4 c4 = *reinterpret_cast<const float4*>(p + 4);
            s[0] += a.x;  s[1] += a.y;  s[2] += a.z;  s[3] += a.w;
            s[4] += c4.x; s[5] += c4.y; s[6] += c4.z; s[7] += c4.w;
            s[8] += p[8];
        }
        float inv = 1.0f / (float)(len > 0 ? len : 1);
        float lg[CC];
#pragma unroll
        for (int c = 0; c < CC; c++) lg[c] = s[c] * inv + bias[c];

        float mx = lg[0];
        int arg = 0;
#pragma unroll
        for (int c = 1; c < CC; c++) {
            if (lg[c] > mx) { mx = lg[c]; arg = c; }
        }
        float se = 0.0f;
#pragma unroll
        for (int c = 0; c < CC; c++) se += expf(lg[c] - mx);
        float lse = mx + logf(se);

        int g = b * SS + w0 + (active ? k : 0);
        int lab = label_ids[g];
        lab = lab < 0 ? 0 : (lab > CC - 1 ? CC - 1 : lab);
        float valid = (active && len > 0) ? 1.0f : 0.0f;
        float nll = (lse - lg[lab]) * valid;

        if (active) pred_out[g] = (float)arg;

        float rn = rsum64(nll);
        float rc = rsum64(valid);
        if (t == 63) {
            nll_part[blockIdx.x] = rn;
            cnt_part[blockIdx.x] = rc;
        }
    }
}

// Finalize: deterministic sum of 1024 block partials -> loss
__global__ __launch_bounds__(1024) void finalize_kernel(
    const float* __restrict__ nll_part,
    const float* __restrict__ cnt_part,
    float* __restrict__ out_loss) {
    __shared__ float sn[16], sc[16];
    int t = threadIdx.x, lane = t & 63, wave = t >> 6;
    float n = nll_part[t];
    float c = cnt_part[t];
    n = rsum64(n);
    c = rsum64(c);
    if (lane == 63) { sn[wave] = n; sc[wave] = c; }
    __syncthreads();
    if (t == 0) {
        float tn = 0.0f, tc = 0.0f;
#pragma unroll
        for (int i = 0; i < 16; i++) { tn += sn[i]; tc += sc[i]; }
        out_loss[0] = tn / fmaxf(tc, 1.0f);
    }
}

extern "C" void kernel_launch(void* const* d_in, const int* in_sizes, int n_in,
                              void* d_out, int out_size, void* d_ws, size_t ws_size,
                              hipStream_t stream) {
    const float* bert = (const float*)d_in[0]; // float32 [B,L,H]
    const float* Wm   = (const float*)d_in[1]; // float32 [H,C]
    const float* bias = (const float*)d_in[2]; // float32 [C]
    // d_in[3] = attention_mask (unused: prefix mask implied by ids_lens)
    const int* ids_lens  = (const int*)d_in[4];
    const int* label_ids = (const int*)d_in[5];
    // d_in[6] = label_mask (derived from ids_lens > 0)

    float* out = (float*)d_out;  // [0]=loss, [1..32768]=pred, float32

    float* nll_part = (float*)d_ws;          // [NBLK]
    float* cnt_part = nll_part + NBLK;       // [NBLK]

    fused_kernel<<<NBLK, 256, 0, stream>>>(bert, Wm, bias, ids_lens, label_ids,
                                           out + 1, nll_part, cnt_part);
    finalize_kernel<<<1, 1024, 0, stream>>>(nll_part, cnt_part, out);
}

// Round 9
// 168.448 us; speedup vs baseline: 1.0541x; 1.0541x over previous
//
#include <hip/hip_runtime.h>

#define BB 64
#define LL 512
#define SS 512
#define HH 768
#define CC 9
#define NROWS (BB * LL)               // 32768 subword rows
#define RLS 12                        // row-logit stride (floats)
#define G1 1024                       // row_gemm blocks
#define ROWS_PER_BLOCK 32             // 4 waves x 8 rows
#define WPS 64                        // words per pool slice
#define G2 (BB * SS / WPS)            // 512 pool blocks

// DPP full-wave (64-lane) sum; total lands in lane 63. Pure VALU, no LDS.
template <int CTRL>
__device__ __forceinline__ float dpp_add(float x) {
    int y = __builtin_amdgcn_update_dpp(0, __float_as_int(x), CTRL, 0xf, 0xf, true);
    return x + __int_as_float(y);
}
__device__ __forceinline__ float rsum64(float x) {
    x = dpp_add<0x111>(x);  // row_shr:1
    x = dpp_add<0x112>(x);  // row_shr:2
    x = dpp_add<0x114>(x);  // row_shr:4
    x = dpp_add<0x118>(x);  // row_shr:8
    x = dpp_add<0x142>(x);  // row_bcast:15
    x = dpp_add<0x143>(x);  // row_bcast:31 -> lane 63 = full sum
    return x;
}

// Kernel 0: W[H][C] -> WT[C][H] in ws (done once; 27 KB, L2-resident after)
__global__ __launch_bounds__(256) void wt_kernel(const float* __restrict__ Wm,
                                                 float* __restrict__ WT_g) {
    int e = blockIdx.x * 256 + threadIdx.x;   // coalesced read of Wm
    if (e < HH * CC) {
        int h = e / CC;
        int c = e - h * CC;
        WT_g[c * HH + h] = Wm[e];
    }
}

// Kernel 1: streaming per-subword-row logits. No LDS, no barriers.
// Each lane's W slice (27 float4) loaded coalesced from global WT (L2-hot).
__global__ __launch_bounds__(256) void row_gemm_kernel(
    const float* __restrict__ bert,   // [B*L, H]
    const float* __restrict__ WT_g,   // [C][H]
    float* __restrict__ RL)           // [NROWS, RLS] ws
{
    int wave = threadIdx.x >> 6;
    int lane = threadIdx.x & 63;
    int hoff = lane * 4;

    float4 wreg[CC][3];
#pragma unroll
    for (int c = 0; c < CC; c++)
#pragma unroll
        for (int c3 = 0; c3 < 3; c3++)
            wreg[c][c3] = *reinterpret_cast<const float4*>(WT_g + c * HH + c3 * 256 + hoff);

    size_t row0 = (size_t)blockIdx.x * ROWS_PER_BLOCK + wave * 8;

#pragma unroll
    for (int r = 0; r < 8; ++r) {
        const float* p = bert + (row0 + r) * HH + hoff;
        float4 f0 = *reinterpret_cast<const float4*>(p);
        float4 f1 = *reinterpret_cast<const float4*>(p + 256);
        float4 f2 = *reinterpret_cast<const float4*>(p + 512);

        float acc[CC];
#pragma unroll
        for (int c = 0; c < CC; c++) {
            acc[c] = f0.x * wreg[c][0].x + f0.y * wreg[c][0].y
                   + f0.z * wreg[c][0].z + f0.w * wreg[c][0].w
                   + f1.x * wreg[c][1].x + f1.y * wreg[c][1].y
                   + f1.z * wreg[c][1].z + f1.w * wreg[c][1].w
                   + f2.x * wreg[c][2].x + f2.y * wreg[c][2].y
                   + f2.z * wreg[c][2].z + f2.w * wreg[c][2].w;
        }
#pragma unroll
        for (int c = 0; c < CC; c++) acc[c] = rsum64(acc[c]);

        if (lane == 63) {
            float* dst = RL + (row0 + r) * RLS;
            float4 s0; s0.x = acc[0]; s0.y = acc[1]; s0.z = acc[2]; s0.w = acc[3];
            float4 s1; s1.x = acc[4]; s1.y = acc[5]; s1.z = acc[6]; s1.w = acc[7];
            *reinterpret_cast<float4*>(dst) = s0;
            *reinterpret_cast<float4*>(dst + 4) = s1;
            dst[8] = acc[8];
        }
    }
}

// Kernel 2: 512 blocks, each owns 64 words of one batch: slice offset +
// mini-scan + pool + softmax/NLL/argmax + per-block partial (no atomics).
__global__ __launch_bounds__(256) void pool_kernel(
    const float* __restrict__ RL,       // [NROWS, RLS]
    const float* __restrict__ bias,     // [C]
    const int* __restrict__ ids_lens,   // [B, S]
    const int* __restrict__ label_ids,  // [B, S]
    float* __restrict__ pred_out,       // d_out + 1
    float* __restrict__ nll_part,       // [G2]
    float* __restrict__ cnt_part)       // [G2]
{
    __shared__ int wlen[WPS], woff[WPS];
    __shared__ float red[4];
    __shared__ int s_start;

    int b = blockIdx.x >> 3;            // batch
    int s8 = blockIdx.x & 7;            // slice in batch
    int w0 = s8 * WPS;                  // first word of slice
    const int* lens = ids_lens + b * SS;

    int t = threadIdx.x, lane = t & 63, wave = t >> 6;

    if (t < WPS) wlen[t] = lens[w0 + t];

    // sum of lens[0..w0) -> slice's first subword row
    int part = 0;
    for (int i = t; i < w0; i += 256) part += lens[i];
    float pf = rsum64((float)part);     // integers < 1536: exact
    if (lane == 63) red[wave] = pf;
    __syncthreads();
    if (t == 0) {
        int run = 0;
#pragma unroll
        for (int k = 0; k < WPS; k++) { woff[k] = run; run += wlen[k]; }
        s_start = (int)(red[0] + red[1] + red[2] + red[3]);
    }
    __syncthreads();

    if (t < 64) {
        int k = t;
        int len = wlen[k];
        int off = s_start + woff[k];
        const float* base = RL + ((size_t)b * LL + off) * RLS;

        float s[CC];
#pragma unroll
        for (int c = 0; c < CC; c++) s[c] = 0.0f;
        for (int j = 0; j < len; ++j) {
            const float* p = base + j * RLS;
            float4 a = *reinterpret_cast<const float4*>(p);
            float4 c4 = *reinterpret_cast<const float4*>(p + 4);
            s[0] += a.x;  s[1] += a.y;  s[2] += a.z;  s[3] += a.w;
            s[4] += c4.x; s[5] += c4.y; s[6] += c4.z; s[7] += c4.w;
            s[8] += p[8];
        }
        float inv = 1.0f / (float)(len > 0 ? len : 1);
        float lg[CC];
#pragma unroll
        for (int c = 0; c < CC; c++) lg[c] = s[c] * inv + bias[c];

        float mx = lg[0];
        int arg = 0;
#pragma unroll
        for (int c = 1; c < CC; c++) {
            if (lg[c] > mx) { mx = lg[c]; arg = c; }
        }
        float se = 0.0f;
#pragma unroll
        for (int c = 0; c < CC; c++) se += expf(lg[c] - mx);
        float lse = mx + logf(se);

        int g = b * SS + w0 + k;
        int lab = label_ids[g];
        lab = lab < 0 ? 0 : (lab > CC - 1 ? CC - 1 : lab);
        float valid = (len > 0) ? 1.0f : 0.0f;
        float nll = (lse - lg[lab]) * valid;

        pred_out[g] = (float)arg;

        float rn = rsum64(nll);
        float rc = rsum64(valid);
        if (t == 63) {
            nll_part[blockIdx.x] = rn;
            cnt_part[blockIdx.x] = rc;
        }
    }
}

// Kernel 3: deterministic reduction of 512 block partials -> loss
__global__ __launch_bounds__(512) void finalize_kernel(
    const float* __restrict__ nll_part,
    const float* __restrict__ cnt_part,
    float* __restrict__ out_loss) {
    __shared__ float sn[8], sc[8];
    int t = threadIdx.x, lane = t & 63, wave = t >> 6;
    float n = rsum64(nll_part[t]);
    float c = rsum64(cnt_part[t]);
    if (lane == 63) { sn[wave] = n; sc[wave] = c; }
    __syncthreads();
    if (t == 0) {
        float tn = 0.0f, tc = 0.0f;
#pragma unroll
        for (int i = 0; i < 8; i++) { tn += sn[i]; tc += sc[i]; }
        out_loss[0] = tn / fmaxf(tc, 1.0f);
    }
}

extern "C" void kernel_launch(void* const* d_in, const int* in_sizes, int n_in,
                              void* d_out, int out_size, void* d_ws, size_t ws_size,
                              hipStream_t stream) {
    const float* bert = (const float*)d_in[0]; // float32 [B,L,H]
    const float* Wm   = (const float*)d_in[1]; // float32 [H,C]
    const float* bias = (const float*)d_in[2]; // float32 [C]
    // d_in[3] = attention_mask (unused: prefix mask implied by ids_lens)
    const int* ids_lens  = (const int*)d_in[4];
    const int* label_ids = (const int*)d_in[5];
    // d_in[6] = label_mask (derived from ids_lens > 0)

    float* out = (float*)d_out;  // [0]=loss, [1..32768]=pred, float32

    float* WT_g     = (float*)d_ws;                    // [C][H]  27648 B
    float* RL       = WT_g + CC * HH;                  // [NROWS][RLS] 1.57 MB
    float* nll_part = RL + (size_t)NROWS * RLS;        // [G2]
    float* cnt_part = nll_part + G2;                   // [G2]

    wt_kernel<<<(HH * CC + 255) / 256, 256, 0, stream>>>(Wm, WT_g);
    row_gemm_kernel<<<G1, 256, 0, stream>>>(bert, WT_g, RL);
    pool_kernel<<<G2, 256, 0, stream>>>(RL, bias, ids_lens, label_ids,
                                        out + 1, nll_part, cnt_part);
    finalize_kernel<<<1, 512, 0, stream>>>(nll_part, cnt_part, out);
}